// Round 5
// baseline (513.538 us; speedup 1.0000x reference)
//
#include <hip/hip_runtime.h>

#define NN 2048
#define DD 128
#define BK 128           // fp32 elements per adj k-tile
#define NT (NN / BK)     // 16 k-tiles

typedef _Float16 f16x8 __attribute__((ext_vector_type(8)));
typedef float f32x4 __attribute__((ext_vector_type(4)));

// ---------------------------------------------------------------------------
// prep: Wt[l][d][k] = fp16(W[l][k][d])
// ---------------------------------------------------------------------------
__global__ __launch_bounds__(256) void prep_kernel(
    const float* __restrict__ W, _Float16* __restrict__ Wt) {
  int idx = blockIdx.x * 256 + threadIdx.x;
  int l = idx >> 14, r = idx & 16383, d = r >> 7, k = r & 127;
  Wt[idx] = (_Float16)W[l * 16384 + k * 128 + d];
}

// ---------------------------------------------------------------------------
// gemmY (layer 0 only): Yt[b][d][n] = sum_k x0[b][n][k] * W0[k][d]
// LDS-free, barrier-free (small: 25 MF of MFMA + 8 MB read).
// ---------------------------------------------------------------------------
__global__ __launch_bounds__(256) void gemmY_kernel(
    const float* __restrict__ X, const _Float16* __restrict__ Wt,
    _Float16* __restrict__ Yt) {
  const int bx = blockIdx.x;
  const int batch = bx & 7, n0 = (bx >> 3) * 32;
  const int tid = threadIdx.x, lane = tid & 63, wave = tid >> 6;
  const int quad = lane >> 4, l15 = lane & 15, d0 = wave * 32;
  f32x4 acc[2][2] = {};
#pragma unroll
  for (int kk = 0; kk < 128; kk += 32) {
    f16x8 a0 = *(const f16x8*)(Wt + (d0 + l15) * DD + kk + quad * 8);
    f16x8 a1 = *(const f16x8*)(Wt + (d0 + 16 + l15) * DD + kk + quad * 8);
#pragma unroll
    for (int fi = 0; fi < 2; ++fi) {
      const float* xp = X + (size_t)(batch * NN + n0 + fi * 16 + l15) * DD + kk + quad * 8;
      float4 x0 = *(const float4*)xp;
      float4 x1 = *(const float4*)(xp + 4);
      f16x8 b = {(_Float16)x0.x, (_Float16)x0.y, (_Float16)x0.z, (_Float16)x0.w,
                 (_Float16)x1.x, (_Float16)x1.y, (_Float16)x1.z, (_Float16)x1.w};
      acc[0][fi] = __builtin_amdgcn_mfma_f32_16x16x32_f16(a0, b, acc[0][fi], 0, 0, 0);
      acc[1][fi] = __builtin_amdgcn_mfma_f32_16x16x32_f16(a1, b, acc[1][fi], 0, 0, 0);
    }
  }
  _Float16* YtB = Yt + (size_t)batch * DD * NN;
#pragma unroll
  for (int df = 0; df < 2; ++df)
#pragma unroll
    for (int fi = 0; fi < 2; ++fi)
#pragma unroll
      for (int r = 0; r < 4; ++r)
        YtB[(size_t)(d0 + df * 16 + quad * 4 + r) * NN + n0 + fi * 16 + l15] =
            (_Float16)acc[df][fi][r];
}

// ---------------------------------------------------------------------------
// agg: Zt[d][i] = sum_j Yt[d][j]*adj[i][j]; act = relu((Z+b)/(rowsum+1))
// adj staged fp32 -> LDS via async global_load_lds (width 16, 1 KB/wave-instr,
// XOR chunk-swizzle folded into the GLOBAL source address so ds_read_b128 is
// bank-conflict-free while LDS dest stays wave-uniform-base+lane*16).
// Yt A-frags: registers, double-buffered (L2-resident).
// Tile 32 i x 128 d, block 256 (4 waves, wave = 32 d). Grid 512 = 2 blk/CU.
// Epilogue fuses the NEXT layer's Linear (act never touches HBM).
// ---------------------------------------------------------------------------
template<bool LAST>
__global__ __launch_bounds__(256) void agg_kernel(
    const float* __restrict__ adj, const _Float16* __restrict__ Yt,
    const float* __restrict__ bias, const _Float16* __restrict__ Wn,
    _Float16* __restrict__ Ytn, float* __restrict__ out) {
  __shared__ __align__(16) float Bsm[2][32 * BK];   // 2 x 16 KB adj tiles
  __shared__ __align__(16) float acts[32][132];     // epilogue activations
  __shared__ float bsh[128];

  const int tid = threadIdx.x, bx = blockIdx.x;
  const int batch = bx & 7, i0 = (bx >> 3) * 32;
  const int wave = tid >> 6, lane = tid & 63;
  const int quad = lane >> 4, l15 = lane & 15;
  const int d0 = wave * 32;
  const int l31 = lane & 31, lh = lane >> 5;

  const float* adjB = adj + (size_t)(batch * NN + i0) * NN;
  const _Float16* YA0 = Yt + (size_t)batch * DD * NN + (size_t)(d0 + l15) * NN + quad * 8;
  const _Float16* YA1 = YA0 + (size_t)16 * NN;

  if (tid < 128) bsh[tid] = bias[tid];

  f32x4 acc[2][2] = {};
  float rs0 = 0.f, rs1 = 0.f;
  f16x8 a[2][4][2];

  // stage one 32x128 fp32 adj tile: 16 wave-instrs total, 4 per wave.
  // wave w stages tile rows 8w..8w+7; instr u covers rows 8w+2u, 8w+2u+1.
  // global chunk order per row rt is XOR-swizzled by (rt&7).
  auto STAGE = [&](int ko, int buf) {
#pragma unroll
    for (int u = 0; u < 4; ++u) {
      const int rt = wave * 8 + u * 2 + lh;                 // per-lane row
      const float* g = adjB + (size_t)rt * NN + ko * BK + ((l31 ^ (rt & 7)) << 2);
      __builtin_amdgcn_global_load_lds(
          (const __attribute__((address_space(1))) unsigned int*)g,
          (__attribute__((address_space(3))) unsigned int*)
              &Bsm[buf][(wave * 8 + u * 2) * BK],           // wave-uniform base
          16, 0, 0);
    }
  };
  auto LOADA = [&](int ko, int buf) {
#pragma unroll
    for (int kk = 0; kk < 4; ++kk) {
      a[buf][kk][0] = *(const f16x8*)(YA0 + ko * BK + kk * 32);
      a[buf][kk][1] = *(const f16x8*)(YA1 + ko * BK + kk * 32);
    }
  };

  STAGE(0, 0);
  LOADA(0, 0);
  __syncthreads();   // compiler emits vmcnt(0) drain: tile 0 + A-regs landed

  for (int ko = 0; ko < NT; ++ko) {
    const int buf = ko & 1;
    if (ko + 1 < NT) { STAGE(ko + 1, buf ^ 1); LOADA(ko + 1, buf ^ 1); }
    const float* Bt = Bsm[buf];
#pragma unroll
    for (int kk = 0; kk < 4; ++kk) {
#pragma unroll
      for (int fi = 0; fi < 2; ++fi) {
        const int row = fi * 16 + l15;
        const int c0 = kk * 8 + quad * 2;          // 16-B chunk index
        const float* rp = Bt + row * BK;
        float4 w0 = *(const float4*)(rp + ((c0 ^ (row & 7)) << 2));
        float4 w1 = *(const float4*)(rp + (((c0 + 1) ^ (row & 7)) << 2));
        float s = ((w0.x + w0.y) + (w0.z + w0.w)) + ((w1.x + w1.y) + (w1.z + w1.w));
        if (fi == 0) rs0 += s; else rs1 += s;
        f16x8 b = {(_Float16)w0.x, (_Float16)w0.y, (_Float16)w0.z, (_Float16)w0.w,
                   (_Float16)w1.x, (_Float16)w1.y, (_Float16)w1.z, (_Float16)w1.w};
        acc[0][fi] = __builtin_amdgcn_mfma_f32_16x16x32_f16(a[buf][kk][0], b, acc[0][fi], 0, 0, 0);
        acc[1][fi] = __builtin_amdgcn_mfma_f32_16x16x32_f16(a[buf][kk][1], b, acc[1][fi], 0, 0, 0);
      }
    }
    __syncthreads();  // drains next tile's DMA + A-regs; protects buf reuse
  }

  // full row sums: reduce across the 4 quads holding disjoint chunk sets
  rs0 += __shfl_xor(rs0, 16); rs0 += __shfl_xor(rs0, 32);
  rs1 += __shfl_xor(rs1, 16); rs1 += __shfl_xor(rs1, 32);
  const float rdv0 = 1.0f / (rs0 + 1.0f);
  const float rdv1 = 1.0f / (rs1 + 1.0f);

  // activations -> LDS (acc col n = l15 matches rdv rows exactly)
#pragma unroll
  for (int af = 0; af < 2; ++af)
#pragma unroll
    for (int r = 0; r < 4; ++r) {
      const int d = d0 + af * 16 + quad * 4 + r;
      const float bv = bsh[d];
      acts[l15][d]      = fmaxf((acc[af][0][r] + bv) * rdv0, 0.f);
      acts[16 + l15][d] = fmaxf((acc[af][1][r] + bv) * rdv1, 0.f);
    }
  __syncthreads();

  if (LAST) {
    float* ob = out + (size_t)(batch * NN + i0) * DD;
#pragma unroll
    for (int u = 0; u < 4; ++u) {
      int c = tid + 256 * u;              // 1024 float4 (32 rows x 32)
      int i = c >> 5, f4 = (c & 31) * 4;
      *(float4*)(ob + (size_t)i * DD + f4) = *(const float4*)&acts[i][f4];
    }
  } else {
    // fused next-layer Linear: Ytn[d][i0+i] = sum_k acts[i][k] * Wn_t[d][k]
    f32x4 acc2[2][2] = {};
#pragma unroll
    for (int kk = 0; kk < 128; kk += 32) {
      f16x8 a0 = *(const f16x8*)(Wn + (d0 + l15) * DD + kk + quad * 8);
      f16x8 a1 = *(const f16x8*)(Wn + (d0 + 16 + l15) * DD + kk + quad * 8);
#pragma unroll
      for (int fi = 0; fi < 2; ++fi) {
        const float* xp = &acts[fi * 16 + l15][kk + quad * 8];
        float4 x0 = *(const float4*)xp;
        float4 x1 = *(const float4*)(xp + 4);
        f16x8 b = {(_Float16)x0.x, (_Float16)x0.y, (_Float16)x0.z, (_Float16)x0.w,
                   (_Float16)x1.x, (_Float16)x1.y, (_Float16)x1.z, (_Float16)x1.w};
        acc2[0][fi] = __builtin_amdgcn_mfma_f32_16x16x32_f16(a0, b, acc2[0][fi], 0, 0, 0);
        acc2[1][fi] = __builtin_amdgcn_mfma_f32_16x16x32_f16(a1, b, acc2[1][fi], 0, 0, 0);
      }
    }
    _Float16* YnB = Ytn + (size_t)batch * DD * NN;
#pragma unroll
    for (int af = 0; af < 2; ++af)
#pragma unroll
      for (int fi = 0; fi < 2; ++fi)
#pragma unroll
        for (int r = 0; r < 4; ++r)
          YnB[(size_t)(d0 + af * 16 + quad * 4 + r) * NN + i0 + fi * 16 + l15] =
              (_Float16)acc2[af][fi][r];
  }
}

extern "C" void kernel_launch(void* const* d_in, const int* in_sizes, int n_in,
                              void* d_out, int out_size, void* d_ws, size_t ws_size,
                              hipStream_t stream) {
  const float* x0   = (const float*)d_in[0];   // [8,2048,128]
  const float* adj  = (const float*)d_in[1];   // [8,2048,2048]
  const float* W    = (const float*)d_in[2];   // [3,128,128]
  const float* bias = (const float*)d_in[3];   // [3,128]
  float* out = (float*)d_out;

  char* ws = (char*)d_ws;
  _Float16* Wt  = (_Float16*)ws;                      // 96 KB fp16 W^T x3
  _Float16* Yt0 = (_Float16*)(ws + (1u << 20));       // 4 MB (reused as Yt2)
  _Float16* Yt1 = (_Float16*)(ws + 6u * (1u << 20));  // 4 MB

  prep_kernel <<<192, 256, 0, stream>>>(W, Wt);
  gemmY_kernel<<<512, 256, 0, stream>>>(x0, Wt, Yt0);
  // layer 1 agg (+ fused layer-2 Linear)
  agg_kernel<false><<<512, 256, 0, stream>>>(adj, Yt0, bias,       Wt + 16384, Yt1, nullptr);
  // layer 2 agg (+ fused layer-3 Linear)
  agg_kernel<false><<<512, 256, 0, stream>>>(adj, Yt1, bias + 128, Wt + 32768, Yt0, nullptr);
  // layer 3 agg -> final fp32 output
  agg_kernel<true ><<<512, 256, 0, stream>>>(adj, Yt0, bias + 256, nullptr,    nullptr, out);
}

// Round 6
// 303.422 us; speedup vs baseline: 1.6925x; 1.6925x over previous
//
#include <hip/hip_runtime.h>

#define NN 2048
#define DD 128
#define BK 128           // fp32 elements per adj k-tile
#define NT (NN / BK)     // 16 k-tiles

typedef _Float16 f16x8 __attribute__((ext_vector_type(8)));
typedef float f32x4 __attribute__((ext_vector_type(4)));

// ---------------------------------------------------------------------------
// prep: Wt[l][d][k] = fp16(W[l][k][d])
// ---------------------------------------------------------------------------
__global__ __launch_bounds__(256) void prep_kernel(
    const float* __restrict__ W, _Float16* __restrict__ Wt) {
  int idx = blockIdx.x * 256 + threadIdx.x;
  int l = idx >> 14, r = idx & 16383, d = r >> 7, k = r & 127;
  Wt[idx] = (_Float16)W[l * 16384 + k * 128 + d];
}

// ---------------------------------------------------------------------------
// gemmY (layer 0 only): Yt[b][d][n] = sum_k x0[b][n][k] * W0[k][d]
// LDS-free, barrier-free.
// ---------------------------------------------------------------------------
__global__ __launch_bounds__(256) void gemmY_kernel(
    const float* __restrict__ X, const _Float16* __restrict__ Wt,
    _Float16* __restrict__ Yt) {
  const int bx = blockIdx.x;
  const int batch = bx & 7, n0 = (bx >> 3) * 32;
  const int tid = threadIdx.x, lane = tid & 63, wave = tid >> 6;
  const int quad = lane >> 4, l15 = lane & 15, d0 = wave * 32;
  f32x4 acc[2][2] = {};
#pragma unroll
  for (int kk = 0; kk < 128; kk += 32) {
    f16x8 a0 = *(const f16x8*)(Wt + (d0 + l15) * DD + kk + quad * 8);
    f16x8 a1 = *(const f16x8*)(Wt + (d0 + 16 + l15) * DD + kk + quad * 8);
#pragma unroll
    for (int fi = 0; fi < 2; ++fi) {
      const float* xp = X + (size_t)(batch * NN + n0 + fi * 16 + l15) * DD + kk + quad * 8;
      float4 x0 = *(const float4*)xp;
      float4 x1 = *(const float4*)(xp + 4);
      f16x8 b = {(_Float16)x0.x, (_Float16)x0.y, (_Float16)x0.z, (_Float16)x0.w,
                 (_Float16)x1.x, (_Float16)x1.y, (_Float16)x1.z, (_Float16)x1.w};
      acc[0][fi] = __builtin_amdgcn_mfma_f32_16x16x32_f16(a0, b, acc[0][fi], 0, 0, 0);
      acc[1][fi] = __builtin_amdgcn_mfma_f32_16x16x32_f16(a1, b, acc[1][fi], 0, 0, 0);
    }
  }
  _Float16* YtB = Yt + (size_t)batch * DD * NN;
#pragma unroll
  for (int df = 0; df < 2; ++df)
#pragma unroll
    for (int fi = 0; fi < 2; ++fi)
#pragma unroll
      for (int r = 0; r < 4; ++r)
        YtB[(size_t)(d0 + df * 16 + quad * 4 + r) * NN + n0 + fi * 16 + l15] =
            (_Float16)acc[df][fi][r];
}

// ---------------------------------------------------------------------------
// agg: Zt[d][i] = sum_j Yt[d][j]*adj[i][j]; act = relu((Z+b)/(rowsum+1))
// adj staged fp32 -> LDS via async global_load_lds (1 KB/wave-instr, XOR
// chunk-swizzle folded into the GLOBAL source address; ds_read_b128 is then
// bank-uniform while the LDS dest stays wave-uniform-base + lane*16).
// Yt A-frags: loaded per k-tile straight from L2-resident Yt (32 VGPRs,
// short-lived — NO persistent double-buffer, so no scratch spill).
// Tile 32 i x 128 d, block 256 (4 waves, wave = 32 d). Grid 512.
// Epilogue fuses the NEXT layer's Linear (activations never touch HBM);
// epilogue LDS overlays the staging buffers (all Bsm reads end at the final
// k-loop barrier).
// ---------------------------------------------------------------------------
template<bool LAST>
__global__ __launch_bounds__(256, 2) void agg_kernel(
    const float* __restrict__ adj, const _Float16* __restrict__ Yt,
    const float* __restrict__ bias, const _Float16* __restrict__ Wn,
    _Float16* __restrict__ Ytn, float* __restrict__ out) {
  __shared__ __align__(16) float Bsm[2][32 * BK];   // 2 x 16 KB adj tiles
  float* acts = &Bsm[0][0];                         // epilogue overlay [32][132]
  __shared__ float bsh[128];

  const int tid = threadIdx.x, bx = blockIdx.x;
  const int batch = bx & 7, i0 = (bx >> 3) * 32;
  const int wave = tid >> 6, lane = tid & 63;
  const int quad = lane >> 4, l15 = lane & 15;
  const int d0 = wave * 32;
  const int l31 = lane & 31, lh = lane >> 5;

  const float* adjB = adj + (size_t)(batch * NN + i0) * NN;
  const _Float16* YA0 = Yt + (size_t)batch * DD * NN + (size_t)(d0 + l15) * NN + quad * 8;
  const _Float16* YA1 = YA0 + (size_t)16 * NN;

  if (tid < 128) bsh[tid] = bias[tid];

  f32x4 acc[2][2] = {};
  float rs0 = 0.f, rs1 = 0.f;

  // stage one 32x128 fp32 adj tile: 16 wave-instrs total, 4 per wave.
  // wave w stages tile rows 8w..8w+7; instr u covers rows 8w+2u, 8w+2u+1.
  // global chunk order per row rt is XOR-swizzled by (rt&7).
  auto STAGE = [&](int ko, int buf) {
#pragma unroll
    for (int u = 0; u < 4; ++u) {
      const int rt = wave * 8 + u * 2 + lh;                 // per-lane row
      const float* g = adjB + (size_t)rt * NN + ko * BK + ((l31 ^ (rt & 7)) << 2);
      __builtin_amdgcn_global_load_lds(
          (const __attribute__((address_space(1))) unsigned int*)g,
          (__attribute__((address_space(3))) unsigned int*)
              &Bsm[buf][(wave * 8 + u * 2) * BK],           // wave-uniform base
          16, 0, 0);
    }
  };

  STAGE(0, 0);
  __syncthreads();   // vmcnt(0) drain: tile 0 landed

  for (int ko = 0; ko < NT; ++ko) {
    const int buf = ko & 1;
    if (ko + 1 < NT) STAGE(ko + 1, buf ^ 1);
    // A-frags for this k-tile (8 x dwordx4 from L2; no persistent buffer)
    f16x8 a[4][2];
#pragma unroll
    for (int kk = 0; kk < 4; ++kk) {
      a[kk][0] = *(const f16x8*)(YA0 + ko * BK + kk * 32);
      a[kk][1] = *(const f16x8*)(YA1 + ko * BK + kk * 32);
    }
    const float* Bt = Bsm[buf];
#pragma unroll
    for (int kk = 0; kk < 4; ++kk) {
#pragma unroll
      for (int fi = 0; fi < 2; ++fi) {
        const int row = fi * 16 + l15;
        const int c0 = kk * 8 + quad * 2;          // 16-B chunk index
        const float* rp = Bt + row * BK;
        float4 w0 = *(const float4*)(rp + ((c0 ^ (row & 7)) << 2));
        float4 w1 = *(const float4*)(rp + (((c0 + 1) ^ (row & 7)) << 2));
        float s = ((w0.x + w0.y) + (w0.z + w0.w)) + ((w1.x + w1.y) + (w1.z + w1.w));
        if (fi == 0) rs0 += s; else rs1 += s;
        f16x8 b = {(_Float16)w0.x, (_Float16)w0.y, (_Float16)w0.z, (_Float16)w0.w,
                   (_Float16)w1.x, (_Float16)w1.y, (_Float16)w1.z, (_Float16)w1.w};
        acc[0][fi] = __builtin_amdgcn_mfma_f32_16x16x32_f16(a[kk][0], b, acc[0][fi], 0, 0, 0);
        acc[1][fi] = __builtin_amdgcn_mfma_f32_16x16x32_f16(a[kk][1], b, acc[1][fi], 0, 0, 0);
      }
    }
    __syncthreads();  // drains next tile's DMA; protects buf reuse
  }

  // full row sums: reduce across the 4 quads holding disjoint chunk sets
  rs0 += __shfl_xor(rs0, 16); rs0 += __shfl_xor(rs0, 32);
  rs1 += __shfl_xor(rs1, 16); rs1 += __shfl_xor(rs1, 32);
  const float rdv0 = 1.0f / (rs0 + 1.0f);
  const float rdv1 = 1.0f / (rs1 + 1.0f);

  // activations -> LDS overlay (acc col n = l15 matches rdv rows exactly)
#pragma unroll
  for (int af = 0; af < 2; ++af)
#pragma unroll
    for (int r = 0; r < 4; ++r) {
      const int d = d0 + af * 16 + quad * 4 + r;
      const float bv = bsh[d];
      acts[l15 * 132 + d]        = fmaxf((acc[af][0][r] + bv) * rdv0, 0.f);
      acts[(16 + l15) * 132 + d] = fmaxf((acc[af][1][r] + bv) * rdv1, 0.f);
    }
  __syncthreads();

  if (LAST) {
    float* ob = out + (size_t)(batch * NN + i0) * DD;
#pragma unroll
    for (int u = 0; u < 4; ++u) {
      int c = tid + 256 * u;              // 1024 float4 (32 rows x 32)
      int i = c >> 5, f4 = (c & 31) * 4;
      *(float4*)(ob + (size_t)i * DD + f4) = *(const float4*)&acts[i * 132 + f4];
    }
  } else {
    // fused next-layer Linear: Ytn[d][i0+i] = sum_k acts[i][k] * Wn_t[d][k]
    f32x4 acc2[2][2] = {};
#pragma unroll
    for (int kk = 0; kk < 128; kk += 32) {
      f16x8 a0 = *(const f16x8*)(Wn + (d0 + l15) * DD + kk + quad * 8);
      f16x8 a1 = *(const f16x8*)(Wn + (d0 + 16 + l15) * DD + kk + quad * 8);
#pragma unroll
      for (int fi = 0; fi < 2; ++fi) {
        const float* xp = &acts[(fi * 16 + l15) * 132 + kk + quad * 8];
        float4 x0 = *(const float4*)xp;
        float4 x1 = *(const float4*)(xp + 4);
        f16x8 b = {(_Float16)x0.x, (_Float16)x0.y, (_Float16)x0.z, (_Float16)x0.w,
                   (_Float16)x1.x, (_Float16)x1.y, (_Float16)x1.z, (_Float16)x1.w};
        acc2[0][fi] = __builtin_amdgcn_mfma_f32_16x16x32_f16(a0, b, acc2[0][fi], 0, 0, 0);
        acc2[1][fi] = __builtin_amdgcn_mfma_f32_16x16x32_f16(a1, b, acc2[1][fi], 0, 0, 0);
      }
    }
    _Float16* YnB = Ytn + (size_t)batch * DD * NN;
#pragma unroll
    for (int af = 0; af < 2; ++af)
#pragma unroll
      for (int fi = 0; fi < 2; ++fi)
#pragma unroll
        for (int r = 0; r < 4; ++r)
          YnB[(size_t)(d0 + af * 16 + quad * 4 + r) * NN + i0 + fi * 16 + l15] =
              (_Float16)acc2[af][fi][r];
  }
}

extern "C" void kernel_launch(void* const* d_in, const int* in_sizes, int n_in,
                              void* d_out, int out_size, void* d_ws, size_t ws_size,
                              hipStream_t stream) {
  const float* x0   = (const float*)d_in[0];   // [8,2048,128]
  const float* adj  = (const float*)d_in[1];   // [8,2048,2048]
  const float* W    = (const float*)d_in[2];   // [3,128,128]
  const float* bias = (const float*)d_in[3];   // [3,128]
  float* out = (float*)d_out;

  char* ws = (char*)d_ws;
  _Float16* Wt  = (_Float16*)ws;                      // 96 KB fp16 W^T x3
  _Float16* Yt0 = (_Float16*)(ws + (1u << 20));       // 4 MB (reused as Yt2)
  _Float16* Yt1 = (_Float16*)(ws + 6u * (1u << 20));  // 4 MB

  prep_kernel <<<192, 256, 0, stream>>>(W, Wt);
  gemmY_kernel<<<512, 256, 0, stream>>>(x0, Wt, Yt0);
  // layer 1 agg (+ fused layer-2 Linear)
  agg_kernel<false><<<512, 256, 0, stream>>>(adj, Yt0, bias,       Wt + 16384, Yt1, nullptr);
  // layer 2 agg (+ fused layer-3 Linear)
  agg_kernel<false><<<512, 256, 0, stream>>>(adj, Yt1, bias + 128, Wt + 32768, Yt0, nullptr);
  // layer 3 agg -> final fp32 output
  agg_kernel<true ><<<512, 256, 0, stream>>>(adj, Yt0, bias + 256, nullptr,    nullptr, out);
}